// Round 8
// baseline (722.097 us; speedup 1.0000x reference)
//
#include <hip/hip_runtime.h>
#include <hip/hip_bf16.h>
#include <stdint.h>

typedef int v4i __attribute__((ext_vector_type(4)));
typedef int v16i __attribute__((ext_vector_type(16)));

#define GM 4096
#define GN 16384
#define GK 4096
#define BM 256
#define BN 256
#define BK 128            // i8 bytes per K-step
#define NTILES (GK / BK)  // 32

__device__ __forceinline__ void gload16(const void* g, void* l) {
  __builtin_amdgcn_global_load_lds(
      (const __attribute__((address_space(1))) void*)g,
      (__attribute__((address_space(3))) void*)l, 16, 0, 0);
}

// ---------------- per-row dynamic quantization (x f32 -> int8 + scale) ----------------
__global__ __launch_bounds__(256) void quant_rows(
    const float* __restrict__ x, int8_t* __restrict__ xq,
    float* __restrict__ xs, int K) {
  const int row = blockIdx.x;
  const int t = threadIdx.x;
  const float4* src = (const float4*)(x + (size_t)row * K) + t * 4;
  float4 v[4];
  float m = 0.f;
#pragma unroll
  for (int i = 0; i < 4; ++i) {
    v[i] = src[i];
    m = fmaxf(m, fmaxf(fmaxf(fabsf(v[i].x), fabsf(v[i].y)),
                       fmaxf(fabsf(v[i].z), fabsf(v[i].w))));
  }
#pragma unroll
  for (int off = 1; off < 64; off <<= 1)
    m = fmaxf(m, __shfl_xor(m, off, 64));
  __shared__ float wmax[4];
  if ((t & 63) == 0) wmax[t >> 6] = m;
  __syncthreads();
  const float gm = fmaxf(fmaxf(wmax[0], wmax[1]), fmaxf(wmax[2], wmax[3]));
  const float scale = (gm + 1e-5f) / 127.0f;  // == ref x_scales
  if (t == 0) xs[row] = scale;
  unsigned packed[4];
#pragma unroll
  for (int i = 0; i < 4; ++i) {
    float fv[4] = {v[i].x, v[i].y, v[i].z, v[i].w};
    unsigned p = 0;
#pragma unroll
    for (int j = 0; j < 4; ++j) {
      int q = (int)rintf(fv[j] / scale);  // RNE, matches np.round
      q = max(-128, min(127, q));
      p |= (unsigned)(q & 0xff) << (8 * j);
    }
    packed[i] = p;
  }
  *(int4*)(xq + (size_t)row * K + t * 16) =
      make_int4((int)packed[0], (int)packed[1], (int)packed[2], (int)packed[3]);
}

// ---------------- W int32 [K][N] -> Wt int8 [N][K] (transpose + pack) ----------------
__global__ __launch_bounds__(256) void transpose_pack(
    const int* __restrict__ W32, int8_t* __restrict__ Wt, int K, int N) {
  __shared__ __align__(16) int8_t tile[64][80];
  const int t = threadIdx.x;
  const int n0 = blockIdx.x * 64;
  const int k0 = blockIdx.y * 64;
  const int ln = t & 63;
  const int wv = t >> 6;
#pragma unroll
  for (int it = 0; it < 16; ++it) {
    const int kk = wv * 16 + it;
    tile[ln][kk] = (int8_t)W32[(size_t)(k0 + kk) * N + n0 + ln];
  }
  __syncthreads();
  const int kb = wv * 16;
  const int4 v = *(const int4*)&tile[ln][kb];
  *(int4*)(Wt + (size_t)(n0 + ln) * K + k0 + kb) = v;
}

// ---- int8 GEMM: 256x256, phase-pipelined (reads for p+1 fly under MFMA of p) ----
// LDS chunk swizzle: logical (row r, 16B-chunk c) stored at chunk c^(r&7);
// global_load_lds writes linearly -> source pre-swizzled (rule #21).
__global__ __launch_bounds__(512, 2) void gemm_i8(
    const int8_t* __restrict__ Xq, const int8_t* __restrict__ Wt,
    const float* __restrict__ xs, const float* __restrict__ wsc,
    const float* __restrict__ bias, float* __restrict__ C) {
  __shared__ __align__(16) int8_t lA[2][BM][BK];  // 64 KB
  __shared__ __align__(16) int8_t lB[2][BN][BK];  // 64 KB

  const int t = threadIdx.x;
  const int lane = t & 63;
  const int w = t >> 6;
  const int wr = w >> 2;  // 0..1 (M half: 128 rows)
  const int wc = w & 3;   // 0..3 (N quarter: 64 cols)
  const int l31 = lane & 31;
  const int kg2 = lane >> 5;

  // bijective XCD swizzle: 1024 blocks = 8 XCD x (16 M x 8 N) rectangles
  const int bid = blockIdx.x;
  const int xcd = bid & 7;
  const int q = bid >> 3;
  const int tm = q & 15;
  const int tn = xcd * 8 + (q >> 4);
  const size_t rowA0 = (size_t)tm * BM;
  const size_t rowB0 = (size_t)tn * BN;

  // staging: 2048 16B-slots per matrix; slot=(i*8+w)*64+lane; r=slot>>3;
  // stored chunk sc=slot&7 holds logical chunk c=sc^(r&7).
  const int8_t* XqB = Xq + rowA0 * GK;
  const int8_t* WtB = Wt + rowB0 * GK;
  int srcOff[4], dstOff[4];
#pragma unroll
  for (int i = 0; i < 4; ++i) {
    const int slot0 = (i * 8 + w) * 64;
    const int slot = slot0 + lane;
    const int r = slot >> 3;
    const int c = (slot & 7) ^ (r & 7);
    srcOff[i] = r * GK + c * 16;
    dstOff[i] = slot0 * 16;  // wave-uniform LDS base
  }

#define STAGE(KT, D)                                                        \
  {                                                                         \
    const int ko = (KT)*BK;                                                 \
    _Pragma("unroll") for (int i = 0; i < 4; ++i)                           \
        gload16(XqB + srcOff[i] + ko, (int8_t*)&lA[(D)][0][0] + dstOff[i]); \
    _Pragma("unroll") for (int i = 0; i < 4; ++i)                           \
        gload16(WtB + srcOff[i] + ko, (int8_t*)&lB[(D)][0][0] + dstOff[i]); \
  }

  // fragment swizzled chunk offsets for k-slice s
  int ck[4];
#pragma unroll
  for (int s = 0; s < 4; ++s) ck[s] = ((2 * s + kg2) ^ (l31 & 7)) * 16;

  v16i acc[4][2] = {};
  v4i areg[4][4], breg[2][4];

#define RD_A(MI, D)                                               \
  {                                                               \
    const int8_t* p = &lA[(D)][wr * 128 + (MI)*32 + l31][0];      \
    _Pragma("unroll") for (int s = 0; s < 4; ++s)                 \
        areg[MI][s] = *(const v4i*)(p + ck[s]);                   \
  }
#define RD_B(NJ, D)                                               \
  {                                                               \
    const int8_t* p = &lB[(D)][wc * 64 + (NJ)*32 + l31][0];       \
    _Pragma("unroll") for (int s = 0; s < 4; ++s)                 \
        breg[NJ][s] = *(const v4i*)(p + ck[s]);                   \
  }

#define MFMA_F(MI, NJ)                                            \
  _Pragma("unroll") for (int s = 0; s < 4; ++s)                   \
      acc[MI][NJ] = __builtin_amdgcn_mfma_i32_32x32x32_i8(        \
          areg[MI][s], breg[NJ][s], acc[MI][NJ], 0, 0, 0);

#define SB __builtin_amdgcn_sched_barrier(0)

  // one K-tile body; D is a literal (0/1) so LDS indexing folds to immediates
#define TILE_BODY(KT, D)                                                     \
  {                                                                          \
    /* ph0: issue G1=B1, gate G0 done (G1 flying), MFMA P0=(A01,B0) */       \
    RD_B(1, D);                                                              \
    SB;                                                                      \
    asm volatile("s_waitcnt lgkmcnt(4)" ::: "memory");                       \
    SB;                                                                      \
    __builtin_amdgcn_s_setprio(1);                                           \
    MFMA_F(0, 0);                                                            \
    MFMA_F(1, 0);                                                            \
    __builtin_amdgcn_s_setprio(0);                                           \
    /* ph1: issue G2=A23, gate G1 done (G2 flying), MFMA P1=(A01,B1) */      \
    RD_A(2, D);                                                              \
    RD_A(3, D);                                                              \
    SB;                                                                      \
    asm volatile("s_waitcnt lgkmcnt(8)" ::: "memory");                       \
    SB;                                                                      \
    __builtin_amdgcn_s_setprio(1);                                           \
    MFMA_F(0, 1);                                                            \
    MFMA_F(1, 1);                                                            \
    __builtin_amdgcn_s_setprio(0);                                           \
    /* ph2: gate all reads of buf D done, MFMA P2=(A23,B0) */                \
    asm volatile("s_waitcnt lgkmcnt(0)" ::: "memory");                       \
    SB;                                                                      \
    __builtin_amdgcn_s_setprio(1);                                           \
    MFMA_F(2, 0);                                                            \
    MFMA_F(3, 0);                                                            \
    __builtin_amdgcn_s_setprio(0);                                           \
    /* ph3: rendezvous (kt+1 resident; buf D read-free CU-wide), stage kt+2, \
       issue G0(kt+1) into regs under MFMA P3=(A23,B1) */                    \
    asm volatile("s_waitcnt vmcnt(0)" ::: "memory");                         \
    __builtin_amdgcn_s_barrier();                                            \
    SB;                                                                      \
    if ((KT) + 2 < NTILES) STAGE((KT) + 2, D);                               \
    SB;                                                                      \
    if ((KT) + 1 < NTILES) {                                                 \
      RD_A(0, (D) ^ 1);                                                      \
      RD_A(1, (D) ^ 1);                                                      \
      RD_B(0, (D) ^ 1);                                                      \
    }                                                                        \
    SB;                                                                      \
    __builtin_amdgcn_s_setprio(1);                                           \
    MFMA_F(2, 1);                                                            \
    MFMA_F(3, 1);                                                            \
    __builtin_amdgcn_s_setprio(0);                                           \
  }

  // prologue: stage tile 0, rendezvous, stage tile 1, pre-issue G0(0)
  STAGE(0, 0);
  asm volatile("s_waitcnt vmcnt(0)" ::: "memory");
  __builtin_amdgcn_s_barrier();
  STAGE(1, 1);
  RD_A(0, 0);
  RD_A(1, 0);
  RD_B(0, 0);
  SB;

  for (int kt = 0; kt < NTILES; kt += 2) {
    TILE_BODY(kt, 0);
    TILE_BODY(kt + 1, 1);
  }

  // epilogue: dequant + bias -> bf16-round -> f32 store
  // 32x32 C/D: col = lane&31, row = (reg&3) + 8*(reg>>2) + 4*(lane>>5)
#pragma unroll
  for (int nj = 0; nj < 2; ++nj) {
    const int col_l = wc * 64 + nj * 32 + l31;
    const float wsv = wsc[rowB0 + col_l];
    const float bv = bias[rowB0 + col_l];
#pragma unroll
    for (int mi = 0; mi < 4; ++mi) {
#pragma unroll
      for (int r = 0; r < 16; ++r) {
        const size_t row =
            rowA0 + wr * 128 + mi * 32 + (r & 3) + 8 * (r >> 2) + 4 * kg2;
        const float f = (float)acc[mi][nj][r] * xs[row] * wsv + bv;
        C[row * GN + rowB0 + col_l] = __bfloat162float(__float2bfloat16(f));
      }
    }
  }
}

extern "C" void kernel_launch(void* const* d_in, const int* in_sizes, int n_in,
                              void* d_out, int out_size, void* d_ws, size_t ws_size,
                              hipStream_t stream) {
  const int M = GM, K = GK, N = GN;
  const float* x = (const float*)d_in[0];
  const int* W32 = (const int*)d_in[1];  // harness pushes integer inputs as int32
  const float* wsc = (const float*)d_in[2];
  const float* bias = (const float*)d_in[3];
  float* out = (float*)d_out;  // reference output dtype is float32 (bf16-rounded)

  // workspace layout: xs (16KB) | Xq (16MB) | Wt (64MB)
  float* xs = (float*)d_ws;
  int8_t* Xq = (int8_t*)d_ws + 16384;
  int8_t* Wt = (int8_t*)d_ws + 16384 + (size_t)M * K;

  transpose_pack<<<dim3(N / 64, K / 64), 256, 0, stream>>>(W32, Wt, K, N);
  quant_rows<<<M, 256, 0, stream>>>(x, Xq, xs, K);
  gemm_i8<<<dim3((M / BM) * (N / BN)), 512, 0, stream>>>(Xq, Wt, xs, wsc, bias,
                                                         out);
}

// Round 9
// 503.384 us; speedup vs baseline: 1.4345x; 1.4345x over previous
//
#include <hip/hip_runtime.h>
#include <hip/hip_bf16.h>
#include <stdint.h>

typedef int v4i __attribute__((ext_vector_type(4)));

#define GM 4096
#define GN 16384
#define GK 4096
#define BM 256
#define BN 256
#define BK 64             // i8 bytes per K-step
#define NT (GK / BK)      // 64 K-tiles
#define SLOT_BYTES 16384  // 256 rows x 64 B per matrix per slot

__device__ __forceinline__ void gload16(const void* g, void* l) {
  __builtin_amdgcn_global_load_lds(
      (const __attribute__((address_space(1))) void*)g,
      (__attribute__((address_space(3))) void*)l, 16, 0, 0);
}

// ---------------- per-row dynamic quantization (x f32 -> int8 + scale) ----------------
__global__ __launch_bounds__(256) void quant_rows(
    const float* __restrict__ x, int8_t* __restrict__ xq,
    float* __restrict__ xs, int K) {
  const int row = blockIdx.x;
  const int t = threadIdx.x;
  const float4* src = (const float4*)(x + (size_t)row * K) + t * 4;
  float4 v[4];
  float m = 0.f;
#pragma unroll
  for (int i = 0; i < 4; ++i) {
    v[i] = src[i];
    m = fmaxf(m, fmaxf(fmaxf(fabsf(v[i].x), fabsf(v[i].y)),
                       fmaxf(fabsf(v[i].z), fabsf(v[i].w))));
  }
#pragma unroll
  for (int off = 1; off < 64; off <<= 1)
    m = fmaxf(m, __shfl_xor(m, off, 64));
  __shared__ float wmax[4];
  if ((t & 63) == 0) wmax[t >> 6] = m;
  __syncthreads();
  const float gm = fmaxf(fmaxf(wmax[0], wmax[1]), fmaxf(wmax[2], wmax[3]));
  const float scale = (gm + 1e-5f) / 127.0f;  // == ref x_scales
  if (t == 0) xs[row] = scale;
  unsigned packed[4];
#pragma unroll
  for (int i = 0; i < 4; ++i) {
    float fv[4] = {v[i].x, v[i].y, v[i].z, v[i].w};
    unsigned p = 0;
#pragma unroll
    for (int j = 0; j < 4; ++j) {
      int q = (int)rintf(fv[j] / scale);  // RNE, matches np.round
      q = max(-128, min(127, q));
      p |= (unsigned)(q & 0xff) << (8 * j);
    }
    packed[i] = p;
  }
  *(int4*)(xq + (size_t)row * K + t * 16) =
      make_int4((int)packed[0], (int)packed[1], (int)packed[2], (int)packed[3]);
}

// ---------------- W int32 [K][N] -> Wt int8 [N][K] (transpose + pack) ----------------
__global__ __launch_bounds__(256) void transpose_pack(
    const int* __restrict__ W32, int8_t* __restrict__ Wt, int K, int N) {
  __shared__ __align__(16) int8_t tile[64][80];
  const int t = threadIdx.x;
  const int n0 = blockIdx.x * 64;
  const int k0 = blockIdx.y * 64;
  const int ln = t & 63;
  const int wv = t >> 6;
#pragma unroll
  for (int it = 0; it < 16; ++it) {
    const int kk = wv * 16 + it;
    tile[ln][kk] = (int8_t)W32[(size_t)(k0 + kk) * N + n0 + ln];
  }
  __syncthreads();
  const int kb = wv * 16;
  const int4 v = *(const int4*)&tile[ln][kb];
  *(int4*)(Wt + (size_t)(n0 + ln) * K + k0 + kb) = v;
}

// ---- int8 GEMM: 256x256 tile, BK=64, 4-slot LDS ring, never-drain counted vmcnt ----
// LDS chunk swizzle: logical (row r, 16B-chunk c in 0..3) stored at chunk c^(r&3);
// global_load_lds writes linearly -> source pre-swizzled (rule #21).
__global__ __launch_bounds__(512, 2) void gemm_i8(
    const int8_t* __restrict__ Xq, const int8_t* __restrict__ Wt,
    const float* __restrict__ xs, const float* __restrict__ wsc,
    const float* __restrict__ bias, float* __restrict__ C) {
  __shared__ __align__(16) int8_t lA[4][BM * BK];  // 64 KB
  __shared__ __align__(16) int8_t lB[4][BN * BK];  // 64 KB

  const int t = threadIdx.x;
  const int lane = t & 63;
  const int w = t >> 6;
  const int wr = w >> 2;  // 0..1 (M half: 128 rows)
  const int wc = w & 3;   // 0..3 (N quarter: 64 cols)
  const int fr = lane & 15;
  const int kg = lane >> 4;

  // bijective XCD swizzle: 1024 blocks = 8 XCD x (16 M x 8 N) rectangles
  const int bid = blockIdx.x;
  const int xcd = bid & 7;
  const int q = bid >> 3;
  const int tm = q & 15;
  const int tn = xcd * 8 + (q >> 4);
  const size_t rowA0 = (size_t)tm * BM;
  const size_t rowB0 = (size_t)tn * BN;

  // staging: tile = 1024 16B-slots per matrix; wave w, instr i in {0,1}:
  // slot0 = (w*2+i)*64; slot = slot0+lane; r = slot>>2; chunk sc = slot&3 holds
  // logical chunk c = sc^(r&3)  -> source pre-swizzled, LDS dest linear.
  const int8_t* XqB = Xq + rowA0 * GK;
  const int8_t* WtB = Wt + rowB0 * GK;
  int srcOff[2], dstOff[2];
#pragma unroll
  for (int i = 0; i < 2; ++i) {
    const int slot0 = (w * 2 + i) * 64;
    const int slot = slot0 + lane;
    const int r = slot >> 2;
    const int c = (slot & 3) ^ (r & 3);
    srcOff[i] = r * GK + c * 16;
    dstOff[i] = slot0 * 16;  // wave-uniform LDS base
  }

#define STAGE(KT, SLOT)                                                     \
  {                                                                         \
    const int ko = (KT)*BK;                                                 \
    _Pragma("unroll") for (int i = 0; i < 2; ++i)                           \
        gload16(XqB + srcOff[i] + ko, &lA[(SLOT)][0] + dstOff[i]);          \
    _Pragma("unroll") for (int i = 0; i < 2; ++i)                           \
        gload16(WtB + srcOff[i] + ko, &lB[(SLOT)][0] + dstOff[i]);          \
  }

  // fragment read: row rr, logical chunk kg stored at (kg^(rr&3)); rr&3 == fr&3
  const int ckk = (kg ^ (fr & 3)) * 16;

  v4i acc[8][4] = {};
  v4i areg[8], breg[4];

#define RD_A(MI, SLOT)                                                      \
  areg[MI] = *(const v4i*)&lA[(SLOT)][(wr * 128 + (MI)*16 + fr) * BK + ckk];
#define RD_B(NJ, SLOT)                                                      \
  breg[NJ] = *(const v4i*)&lB[(SLOT)][(wc * 64 + (NJ)*16 + fr) * BK + ckk];

#define SB __builtin_amdgcn_sched_barrier(0)

#define BODY(T, SLOT)                                                        \
  {                                                                         \
    /* rendezvous: my 4 stage-instrs of tile T landed (8 newer may fly);    \
       barrier => CU-wide resident AND all reads of slot (SLOT+3)&3 done */ \
    asm volatile("s_waitcnt vmcnt(8)" ::: "memory");                        \
    __builtin_amdgcn_s_barrier();                                           \
    STAGE(((T) + 3) & (NT - 1), ((SLOT) + 3) & 3);                          \
    SB;                                                                     \
    RD_A(0, SLOT); RD_A(1, SLOT); RD_A(2, SLOT); RD_A(3, SLOT);             \
    RD_B(0, SLOT); RD_B(1, SLOT);                                           \
    SB;                                                                     \
    RD_B(2, SLOT); RD_B(3, SLOT);                                           \
    SB;                                                                     \
    RD_A(4, SLOT); RD_A(5, SLOT); RD_A(6, SLOT); RD_A(7, SLOT);             \
    SB;                                                                     \
    asm volatile("s_waitcnt lgkmcnt(6)" ::: "memory"); /* A0-3,B0,B1 */     \
    SB;                                                                     \
    __builtin_amdgcn_s_setprio(1);                                          \
    _Pragma("unroll") for (int mi = 0; mi < 4; ++mi)                        \
        _Pragma("unroll") for (int nj = 0; nj < 2; ++nj)                    \
            acc[mi][nj] = __builtin_amdgcn_mfma_i32_16x16x64_i8(            \
                areg[mi], breg[nj], acc[mi][nj], 0, 0, 0);                  \
    __builtin_amdgcn_s_setprio(0);                                          \
    asm volatile("s_waitcnt lgkmcnt(4)" ::: "memory"); /* +B2,B3 */         \
    SB;                                                                     \
    __builtin_amdgcn_s_setprio(1);                                          \
    _Pragma("unroll") for (int mi = 0; mi < 4; ++mi)                        \
        _Pragma("unroll") for (int nj = 2; nj < 4; ++nj)                    \
            acc[mi][nj] = __builtin_amdgcn_mfma_i32_16x16x64_i8(            \
                areg[mi], breg[nj], acc[mi][nj], 0, 0, 0);                  \
    __builtin_amdgcn_s_setprio(0);                                          \
    asm volatile("s_waitcnt lgkmcnt(0)" ::: "memory"); /* +A4-7 */          \
    SB;                                                                     \
    __builtin_amdgcn_s_setprio(1);                                          \
    _Pragma("unroll") for (int mi = 4; mi < 8; ++mi)                        \
        _Pragma("unroll") for (int nj = 0; nj < 4; ++nj)                    \
            acc[mi][nj] = __builtin_amdgcn_mfma_i32_16x16x64_i8(            \
                areg[mi], breg[nj], acc[mi][nj], 0, 0, 0);                  \
    __builtin_amdgcn_s_setprio(0);                                          \
  }

  // prologue: fill ring 3 deep (12 gloads outstanding)
  STAGE(0, 0);
  STAGE(1, 1);
  STAGE(2, 2);

  for (int kt = 0; kt < NT; kt += 4) {
    BODY(kt, 0);
    BODY(kt + 1, 1);
    BODY(kt + 2, 2);
    BODY(kt + 3, 3);
  }

  // epilogue: dequant + bias -> bf16-round -> f32 store
  // 16x16 C/D: col = lane&15, row = (lane>>4)*4 + reg
#pragma unroll
  for (int nj = 0; nj < 4; ++nj) {
    const int col_l = wc * 64 + nj * 16 + fr;
    const float wsv = wsc[rowB0 + col_l];
    const float bv = bias[rowB0 + col_l];
#pragma unroll
    for (int mi = 0; mi < 8; ++mi) {
#pragma unroll
      for (int r = 0; r < 4; ++r) {
        const size_t row = rowA0 + wr * 128 + mi * 16 + kg * 4 + r;
        const float f = (float)acc[mi][nj][r] * xs[row] * wsv + bv;
        C[row * GN + rowB0 + col_l] = __bfloat162float(__float2bfloat16(f));
      }
    }
  }
}

extern "C" void kernel_launch(void* const* d_in, const int* in_sizes, int n_in,
                              void* d_out, int out_size, void* d_ws, size_t ws_size,
                              hipStream_t stream) {
  const int M = GM, K = GK, N = GN;
  const float* x = (const float*)d_in[0];
  const int* W32 = (const int*)d_in[1];  // harness pushes integer inputs as int32
  const float* wsc = (const float*)d_in[2];
  const float* bias = (const float*)d_in[3];
  float* out = (float*)d_out;  // reference output dtype is float32 (bf16-rounded)

  // workspace layout: xs (16KB) | Xq (16MB) | Wt (64MB)
  float* xs = (float*)d_ws;
  int8_t* Xq = (int8_t*)d_ws + 16384;
  int8_t* Wt = (int8_t*)d_ws + 16384 + (size_t)M * K;

  transpose_pack<<<dim3(N / 64, K / 64), 256, 0, stream>>>(W32, Wt, K, N);
  quant_rows<<<M, 256, 0, stream>>>(x, Xq, xs, K);
  gemm_i8<<<dim3((M / BM) * (N / BN)), 512, 0, stream>>>(Xq, Wt, xs, wsc, bias,
                                                         out);
}

// Round 10
// 433.164 us; speedup vs baseline: 1.6670x; 1.1621x over previous
//
#include <hip/hip_runtime.h>
#include <hip/hip_bf16.h>
#include <stdint.h>

typedef int v4i __attribute__((ext_vector_type(4)));

#define GM 4096
#define GN 16384
#define GK 4096
#define BM 256
#define BN 256
#define BK 64         // i8 bytes per K-step
#define NT (GK / BK)  // 64 K-tiles

__device__ __forceinline__ void gload16(const void* g, void* l) {
  __builtin_amdgcn_global_load_lds(
      (const __attribute__((address_space(1))) void*)g,
      (__attribute__((address_space(3))) void*)l, 16, 0, 0);
}

// ---------------- per-row dynamic quantization (x f32 -> int8 + scale) ----------------
__global__ __launch_bounds__(256) void quant_rows(
    const float* __restrict__ x, int8_t* __restrict__ xq,
    float* __restrict__ xs, int K) {
  const int row = blockIdx.x;
  const int t = threadIdx.x;
  const float4* src = (const float4*)(x + (size_t)row * K) + t * 4;
  float4 v[4];
  float m = 0.f;
#pragma unroll
  for (int i = 0; i < 4; ++i) {
    v[i] = src[i];
    m = fmaxf(m, fmaxf(fmaxf(fabsf(v[i].x), fabsf(v[i].y)),
                       fmaxf(fabsf(v[i].z), fabsf(v[i].w))));
  }
#pragma unroll
  for (int off = 1; off < 64; off <<= 1)
    m = fmaxf(m, __shfl_xor(m, off, 64));
  __shared__ float wmax[4];
  if ((t & 63) == 0) wmax[t >> 6] = m;
  __syncthreads();
  const float gm = fmaxf(fmaxf(wmax[0], wmax[1]), fmaxf(wmax[2], wmax[3]));
  const float scale = (gm + 1e-5f) / 127.0f;  // == ref x_scales
  if (t == 0) xs[row] = scale;
  unsigned packed[4];
#pragma unroll
  for (int i = 0; i < 4; ++i) {
    float fv[4] = {v[i].x, v[i].y, v[i].z, v[i].w};
    unsigned p = 0;
#pragma unroll
    for (int j = 0; j < 4; ++j) {
      int q = (int)rintf(fv[j] / scale);  // RNE, matches np.round
      q = max(-128, min(127, q));
      p |= (unsigned)(q & 0xff) << (8 * j);
    }
    packed[i] = p;
  }
  *(int4*)(xq + (size_t)row * K + t * 16) =
      make_int4((int)packed[0], (int)packed[1], (int)packed[2], (int)packed[3]);
}

// ------- W int32 [K][N] -> Wt2 int8 in MFMA-fragment order -------
// Wt2[tn][kt][f][lane][16B]: lane l holds col n = tn*256 + f*16 + (l&15),
// k = kt*64 + (l>>4)*16 .. +16.  One fragment = 1 KB contiguous.
__global__ __launch_bounds__(256) void transpose_pack(
    const int* __restrict__ W32, int8_t* __restrict__ Wt2, int K, int N) {
  __shared__ __align__(16) int8_t tile[64][80];
  const int t = threadIdx.x;
  const int n0 = blockIdx.x * 64;
  const int k0 = blockIdx.y * 64;
  const int ln = t & 63;
  const int wv = t >> 6;
#pragma unroll
  for (int it = 0; it < 16; ++it) {
    const int kk = wv * 16 + it;
    tile[ln][kk] = (int8_t)W32[(size_t)(k0 + kk) * N + n0 + ln];
  }
  __syncthreads();
  // wave wv emits fragment f = base + wv (16 cols x 64 k)
  const int lane = ln;
  const int4 v = *(const int4*)&tile[wv * 16 + (lane & 15)][(lane >> 4) * 16];
  const int tn = n0 >> 8;
  const int kt = k0 >> 6;
  const int f = ((n0 >> 4) & 15) + wv;
  *(int4*)(Wt2 + (((size_t)(tn * 64 + kt) * 16 + f) * 64 + lane) * 16) = v;
}

// ---- int8 GEMM: A via 4-slot LDS ring (never-drain), B direct global->VGPR, ----
// ---- 3-tile prefetch depth on both streams, one barrier per K-tile.          ----
__global__ __launch_bounds__(512, 2) void gemm_i8(
    const int8_t* __restrict__ Xq, const int8_t* __restrict__ Wt2,
    const float* __restrict__ xs, const float* __restrict__ wsc,
    const float* __restrict__ bias, float* __restrict__ C) {
  __shared__ __align__(16) int8_t lA[4][BM * BK];  // 64 KB total

  const int t = threadIdx.x;
  const int lane = t & 63;
  const int w = t >> 6;
  const int wr = w >> 2;  // 0..1 (M half: 128 rows)
  const int wc = w & 3;   // 0..3 (N quarter: 64 cols)
  const int fr = lane & 15;
  const int kg = lane >> 4;

  // bijective XCD swizzle: 1024 blocks = 8 XCD x (16 M x 8 N) rectangles
  const int bid = blockIdx.x;
  const int xcd = bid & 7;
  const int q = bid >> 3;
  const int tm = q & 15;
  const int tn = xcd * 8 + (q >> 4);
  const size_t rowA0 = (size_t)tm * BM;
  const size_t rowB0 = (size_t)tn * BN;

  // A staging: tile = 1024 16B-slots; wave w instr i: slot0=(w*2+i)*64;
  // slot = slot0+lane; r = slot>>2; storage chunk sc = slot&3 holds logical
  // chunk c = sc ^ ((r>>2)&3)  (source pre-swizzled, LDS dest linear).
  const int8_t* XqB = Xq + rowA0 * GK;
  int srcOff[2], dstOff[2];
#pragma unroll
  for (int i = 0; i < 2; ++i) {
    const int slot0 = (w * 2 + i) * 64;
    const int slot = slot0 + lane;
    const int r = slot >> 2;
    const int c = (slot & 3) ^ ((r >> 2) & 3);
    srcOff[i] = r * GK + c * 16;
    dstOff[i] = slot0 * 16;  // wave-uniform LDS base
  }

#define STAGE(KT, SLOT)                                              \
  {                                                                  \
    const int ko = (KT)*BK;                                          \
    _Pragma("unroll") for (int i = 0; i < 2; ++i)                    \
        gload16(XqB + srcOff[i] + ko, &lA[(SLOT)][0] + dstOff[i]);   \
  }

  // B fragment base for this wave: f = wc*4 + nj
  const int8_t* bq = Wt2 + (size_t)tn * 1048576 + wc * 4096 + lane * 16;

  v4i acc[8][4] = {};
  v4i areg[8], breg[4][4];  // breg[slot][nj]

  // inline-asm B loads: no compiler-inserted waits; gated by our vmcnt(12)
#define LOADB(KT, S)                                                          \
  {                                                                           \
    const int8_t* bp = bq + (size_t)(KT)*16384;                               \
    _Pragma("unroll") for (int nj = 0; nj < 4; ++nj)                          \
        asm volatile("global_load_dwordx4 %0, %1, off"                        \
                     : "=v"(breg[S][nj])                                      \
                     : "v"(bp + nj * 1024)                                    \
                     : "memory");                                             \
  }

  // A fragment read: row rr = wr*128+mi*16+fr, logical chunk kg stored at
  // kg ^ (fr>>2)  (since (rr>>2)&3 == fr>>2)
  const int ckk = (kg ^ (fr >> 2)) * 16;
#define RD_A(MI, SLOT)                                                        \
  areg[MI] = *(const v4i*)&lA[(SLOT)][(wr * 128 + (MI)*16 + fr) * BK + ckk];

#define SB __builtin_amdgcn_sched_barrier(0)

#define BODY(T, SLOT)                                                         \
  {                                                                           \
    /* entry gate: batch T fully landed (batches T+1,T+2 = 12 may fly) */     \
    asm volatile("s_waitcnt vmcnt(12)" ::: "memory");                         \
    __builtin_amdgcn_s_barrier(); /* A(T) resident CU-wide; slot free */      \
    SB;                                                                       \
    STAGE(((T) + 3) & (NT - 1), ((SLOT) + 3) & 3);                            \
    LOADB(((T) + 3) & (NT - 1), ((SLOT) + 3) & 3);                            \
    SB;                                                                       \
    RD_A(0, SLOT); RD_A(1, SLOT); RD_A(2, SLOT); RD_A(3, SLOT);               \
    SB;                                                                       \
    RD_A(4, SLOT); RD_A(5, SLOT); RD_A(6, SLOT); RD_A(7, SLOT);               \
    SB;                                                                       \
    asm volatile("s_waitcnt lgkmcnt(4)" ::: "memory"); /* A0-3 ready */       \
    SB;                                                                       \
    __builtin_amdgcn_s_setprio(1);                                            \
    _Pragma("unroll") for (int mi = 0; mi < 4; ++mi)                          \
        _Pragma("unroll") for (int nj = 0; nj < 4; ++nj)                      \
            acc[mi][nj] = __builtin_amdgcn_mfma_i32_16x16x64_i8(              \
                areg[mi], breg[SLOT][nj], acc[mi][nj], 0, 0, 0);              \
    __builtin_amdgcn_s_setprio(0);                                            \
    asm volatile("s_waitcnt lgkmcnt(0)" ::: "memory"); /* A4-7 ready */       \
    SB;                                                                       \
    __builtin_amdgcn_s_setprio(1);                                            \
    _Pragma("unroll") for (int mi = 4; mi < 8; ++mi)                          \
        _Pragma("unroll") for (int nj = 0; nj < 4; ++nj)                      \
            acc[mi][nj] = __builtin_amdgcn_mfma_i32_16x16x64_i8(              \
                areg[mi], breg[SLOT][nj], acc[mi][nj], 0, 0, 0);              \
    __builtin_amdgcn_s_setprio(0);                                            \
  }

  // prologue: issue batches 0,1,2 (A-stage + B-loads each)
  STAGE(0, 0);
  LOADB(0, 0);
  STAGE(1, 1);
  LOADB(1, 1);
  STAGE(2, 2);
  LOADB(2, 2);

  for (int kt = 0; kt < NT; kt += 4) {
    BODY(kt, 0);
    BODY(kt + 1, 1);
    BODY(kt + 2, 2);
    BODY(kt + 3, 3);
  }
  // drain stale prefetches so late writebacks can't clobber reused regs
  asm volatile("s_waitcnt vmcnt(0) lgkmcnt(0)" ::: "memory");
  SB;

  // epilogue: dequant + bias -> bf16-round -> f32 store
  // 16x16 C/D: col = lane&15, row = (lane>>4)*4 + reg
#pragma unroll
  for (int nj = 0; nj < 4; ++nj) {
    const int col_l = wc * 64 + nj * 16 + fr;
    const float wsv = wsc[rowB0 + col_l];
    const float bv = bias[rowB0 + col_l];
#pragma unroll
    for (int mi = 0; mi < 8; ++mi) {
#pragma unroll
      for (int r = 0; r < 4; ++r) {
        const size_t row = rowA0 + wr * 128 + mi * 16 + kg * 4 + r;
        const float f = (float)acc[mi][nj][r] * xs[row] * wsv + bv;
        C[row * GN + rowB0 + col_l] = __bfloat162float(__float2bfloat16(f));
      }
    }
  }
}

extern "C" void kernel_launch(void* const* d_in, const int* in_sizes, int n_in,
                              void* d_out, int out_size, void* d_ws, size_t ws_size,
                              hipStream_t stream) {
  const int M = GM, K = GK, N = GN;
  const float* x = (const float*)d_in[0];
  const int* W32 = (const int*)d_in[1];  // harness pushes integer inputs as int32
  const float* wsc = (const float*)d_in[2];
  const float* bias = (const float*)d_in[3];
  float* out = (float*)d_out;  // reference output dtype is float32 (bf16-rounded)

  // workspace layout: xs (16KB) | Xq (16MB) | Wt2 (64MB packed)
  float* xs = (float*)d_ws;
  int8_t* Xq = (int8_t*)d_ws + 16384;
  int8_t* Wt2 = (int8_t*)d_ws + 16384 + (size_t)M * K;

  transpose_pack<<<dim3(N / 64, K / 64), 256, 0, stream>>>(W32, Wt2, K, N);
  quant_rows<<<M, 256, 0, stream>>>(x, Xq, xs, K);
  gemm_i8<<<dim3((M / BM) * (N / BN)), 512, 0, stream>>>(Xq, Wt2, xs, wsc, bias,
                                                         out);
}